// Round 7
// baseline (462.396 us; speedup 1.0000x reference)
//
#include <hip/hip_runtime.h>

// Problem constants (from reference): T=1024, B=32, D=768, L=48
#define T_ 1024
#define B_ 32
#define D_ 768
#define L_ 48
#define TB_ (T_ * B_)   // 32768 rows of the emissions GEMM

typedef __attribute__((ext_vector_type(4))) float f32x4;

// ---------------------------------------------------------------------------
// Kernel A: E = exp(feats @ W + b)   (fp32, M=32768 N=48 K=768)
// 64-row tiles x 256 threads, grid = 512 -> 2 blocks/CU (2 waves/SIMD TLP;
// the 128-row/1-block-per-CU version ran ~8x its compute floor and explicit
// double-buffering was measured useless).  Per-thread state ~50 VGPRs
// (acc[2][6], fv[2], wv4[6]) so no allocator cap can force spills.
// feats staged via global_load_lds (width 16) into an UNPADDED 64x64 LDS
// buffer with XOR swizzle (slot = gchunk ^ (row&7)); W staged through VGPRs
// into wbuf padded 68.  LDS = 16K + 13.3K = 29.4 KiB -> 2 blocks/CU fits.
// ---------------------------------------------------------------------------
__global__ __launch_bounds__(256, 2) void emis_gemm(
    const float* __restrict__ feats, const float* __restrict__ W,
    const float* __restrict__ bias, float* __restrict__ E) {
  __shared__ float fbuf[64 * 64];    // row-major, 16 chunks of 16B per row
  __shared__ float wbuf[48 * 68];    // wbuf[j][ko], padded
  const int tid = threadIdx.x;
  const int wv = tid >> 6;           // wave id 0..3
  const int lane = tid & 63;
  const int cg = tid & 7;            // col group -> cols c0..c0+5
  const int rg = tid >> 3;           // row group 0..31 -> rows rg, rg+32
  const int c0 = cg * 6;
  const int rowbase = blockIdx.x * 64;
  const int r7 = rg & 7;
  const int r_in = lane >> 4;        // 0..3 row-within-gload_lds
  const int slot = lane & 15;

  float acc[2][6];
#pragma unroll
  for (int i = 0; i < 2; i++)
#pragma unroll
    for (int c = 0; c < 6; c++) acc[i][c] = 0.f;

  for (int kc = 0; kc < D_; kc += 64) {
    __syncthreads();  // previous chunk's reads complete before overwrite

    // feats chunk: 4 global_load_lds per wave, 4 rows (64 slots) each.
    // LDS slot (r, s) holds global chunk (s ^ (r&7)) -> pre-swizzled source,
    // linear LDS dest (wave-uniform base + lane*16B).
#pragma unroll
    for (int inst = 0; inst < 4; inst++) {
      const int rowstart = wv * 16 + inst * 4;
      const int r = rowstart + r_in;
      const int gch = slot ^ (r & 7);
      const float* g = feats + (size_t)(rowbase + r) * D_ + kc + gch * 4;
      float* l = fbuf + rowstart * 64;  // wave-uniform base
      __builtin_amdgcn_global_load_lds(
          (const __attribute__((address_space(1))) uint32_t*)g,
          (__attribute__((address_space(3))) uint32_t*)l, 16, 0, 0);
    }

    // W chunk transposed: wbuf[j][ko] = W[kc+ko][j]
#pragma unroll
    for (int i = 0; i < 12; i++) {
      const int idx = tid + i * 256;  // 0..3071
      const int ko = idx / 48;
      const int j = idx - ko * 48;
      wbuf[j * 68 + ko] = W[(kc + ko) * L_ + j];
    }

    __syncthreads();  // drains vmcnt (global_load_lds) + lgkm (ds_write)

#pragma unroll 4
    for (int k4 = 0; k4 < 16; k4++) {
      float4 fv[2];
      float4 wv4[6];
      const int sch = (k4 ^ r7) << 2;  // swizzled chunk offset (floats)
#pragma unroll
      for (int i = 0; i < 2; i++)
        fv[i] = *(const float4*)(fbuf + (rg + 32 * i) * 64 + sch);
#pragma unroll
      for (int cc = 0; cc < 6; cc++)
        wv4[cc] = *(const float4*)(wbuf + (c0 + cc) * 68 + k4 * 4);
#pragma unroll
      for (int i = 0; i < 2; i++) {
#pragma unroll
        for (int cc = 0; cc < 6; cc++) {
          acc[i][cc] = fmaf(fv[i].x, wv4[cc].x, acc[i][cc]);
          acc[i][cc] = fmaf(fv[i].y, wv4[cc].y, acc[i][cc]);
          acc[i][cc] = fmaf(fv[i].z, wv4[cc].z, acc[i][cc]);
          acc[i][cc] = fmaf(fv[i].w, wv4[cc].w, acc[i][cc]);
        }
      }
    }
  }

  // epilogue: E = exp(acc + bias), rows rg, rg+32, cols c0..c0+5
#pragma unroll
  for (int i = 0; i < 2; i++) {
    float* dst = E + (size_t)(rowbase + rg + 32 * i) * L_ + c0;
#pragma unroll
    for (int cc = 0; cc < 6; cc += 2) {
      float2 v;
      v.x = __expf(acc[i][cc + 0] + bias[c0 + cc + 0]);
      v.y = __expf(acc[i][cc + 1] + bias[c0 + cc + 1]);
      *(float2*)(dst + cc) = v;
    }
  }
}

// ---------------------------------------------------------------------------
// Kernel B: one block (128 threads) per batch element; wave 0 = unconstrained
// forward, wave 1 = constrained partial.  Scaled-probability recurrence.
// Round-5 evidence: VGPR_Count=64 with ~85 regs of demand -> P[48] lived in
// SCRATCH; 574 cyc/step vs ~300 modeled.  P now lives in LDS where it cannot
// spill:
//   - pbuf row stride 52 floats: rows 16B-aligned (208 B); row starts hit
//     all 8 four-bank groups across j&7; residual ~6-way aliasing IS the
//     768B/instr LDS bandwidth floor (48 lanes x 16B) -> layout-optimal.
//     Lane j reads only its own row: 12 ds_read_b128/step, independent of
//     the serial state dependence (issue in the broadcast-latency shadow).
//   - state broadcast via sbuf double-buffer (12 broadcast ds_read_b128,
//     conflict-free; 1 stride-1 ds_write_b32 publish).
//   - rescale (t%8==1) with zero cross-lane ops: m = max over the same
//     broadcast state reads (lane-uniform by construction), folded into
//     this step's emission multiply; logacc += log(m).
//   - register demand now ~40 -> no spill at any allocator target.
// Parity: state(t=0) in parity 0; step i reads i&1, writes (i+1)&1; 4-step
// body keeps bodies starting at parity 0; tail continues from parity 0.
// ---------------------------------------------------------------------------
__global__ __launch_bounds__(128) void crf_scan(
    const float* __restrict__ E, const int* __restrict__ tags,
    const int* __restrict__ lens, const float* __restrict__ begin,
    const float* __restrict__ trans, const float* __restrict__ endt,
    const int* __restrict__ bc, const int* __restrict__ ec,
    const int* __restrict__ tc, float* __restrict__ out) {
  __shared__ __align__(16) float sbuf[2][2][64];   // [wave][parity][slot]
  __shared__ __align__(16) float pbuf[2][48 * 52]; // [wave][row j * 52 + k]
  __shared__ float lzbuf[2];
  const int b = blockIdx.x;
  const int wv = threadIdx.x >> 6;   // 0 = fwd, 1 = constrained partial
  const int lane = threadIdx.x & 63;
  const bool act = lane < L_;
  const bool par = (wv == 1);
  const int len = lens[b];            // in [512, 1024]
  const int stride = B_ * L_;
  const int base = b * L_ + (act ? lane : 0);  // clamped for lanes 48..63

  // P row j -> LDS: pbuf[wv][j*52 + k] = exp(trans[j][k]), constraint-masked
  // on wave 1.  Same-wave RAW (lane j writes row j, reads row j) is ordered
  // by the compiler's lgkmcnt; no barrier needed.
  if (act) {
#pragma unroll
    for (int k = 0; k < L_; k++) {
      float v = __expf(trans[lane * L_ + k]);
      if (par && tc[lane * L_ + k]) v = 0.f;
      pbuf[wv][lane * 52 + k] = v;
    }
  }
  // inactive lanes point at row 0 (reads in-bounds; results unused)
  const f32x4* prow = (const f32x4*)(pbuf[wv] + (act ? lane : 0) * 52);

  // init: a0 = E[0]*exp(begin); wave 1 additionally masked by bc/tags[0]
  float a = 0.f;
  if (act) {
    a = E[base] * __expf(begin[lane]);
    if (par && (bc[lane] || tags[base])) a = 0.f;
  }
  float logacc = 0.f;

  sbuf[wv][0][lane] = a;  // state(t=0) -> parity 0

  // One recurrence step.  resc: divide this step's output by m = max of the
  // input state (read via the same broadcast loads) and log-accumulate m.
  auto step = [&](int i, float ev, int tg, bool resc) {
    const f32x4* src = (const f32x4*)sbuf[wv][i & 1];
    float s0 = 0.f, s1 = 0.f, s2 = 0.f, s3 = 0.f;
    f32x4 mx = {0.f, 0.f, 0.f, 0.f};  // state is non-negative
#pragma unroll
    for (int c = 0; c < 12; c++) {
      const f32x4 pq = prow[c];   // own-row P chunk (independent of state)
      const f32x4 q = src[c];     // broadcast state chunk
      if (resc) {
        mx.x = fmaxf(mx.x, q.x);
        mx.y = fmaxf(mx.y, q.y);
        mx.z = fmaxf(mx.z, q.z);
        mx.w = fmaxf(mx.w, q.w);
      }
      s0 = fmaf(q.x, pq.x, s0);
      s1 = fmaf(q.y, pq.y, s1);
      s2 = fmaf(q.z, pq.z, s2);
      s3 = fmaf(q.w, pq.w, s3);
    }
    float evp = ev;
    if (resc) {
      float m = fmaxf(fmaxf(mx.x, mx.y), fmaxf(mx.z, mx.w));
      m = fmaxf(m, 1e-30f);     // uniform across lanes (same broadcast data)
      logacc += __logf(m);
      evp = ev * (1.f / m);
    }
    float u = ((s0 + s1) + (s2 + s3)) * evp;
    if (tg) u = 0.f;  // tg is always 0 on wave 0
    a = u;
    sbuf[wv][(i + 1) & 1][lane] = u;  // publish for the next step
  };

  // preload emissions/tags for t = 1..4 (len >= 512 so always valid)
  float e4[4];
  int tg4[4];
#pragma unroll
  for (int i = 0; i < 4; i++) {
    e4[i] = E[(size_t)(1 + i) * stride + base];
    tg4[i] = par ? tags[(size_t)(1 + i) * stride + base] : 0;
  }

  int t = 1;  // bodies start at t == 1 (mod 4); rescale when t == 1 (mod 8)
  for (; t + 4 <= len; t += 4) {
    float p4[4];
    int q4[4];
#pragma unroll
    for (int i = 0; i < 4; i++) {
      int tt = t + 4 + i;
      tt = (tt < len) ? tt : (len - 1);
      p4[i] = E[(size_t)tt * stride + base];
      q4[i] = par ? tags[(size_t)tt * stride + base] : 0;
    }
    if ((t & 7) == 1) {
      step(0, e4[0], tg4[0], true);   // specialized resc=true expansion
    } else {
      step(0, e4[0], tg4[0], false);
    }
    step(1, e4[1], tg4[1], false);
    step(2, e4[2], tg4[2], false);
    step(3, e4[3], tg4[3], false);
#pragma unroll
    for (int i = 0; i < 4; i++) { e4[i] = p4[i]; tg4[i] = q4[i]; }
  }
  // tail: at most 3 steps; e4 holds times t..t+3 (clamped); parity continues
#pragma unroll
  for (int i = 0; i < 4; i++) {
    if (t + i < len) step(i, e4[i], tg4[i], false);
  }

  // readout: logZ = logacc + log(sum_j a[j]*exp(end[j]))
  float z = 0.f;
  if (act) {
    float ez = __expf(endt[lane]);
    if (par && ec[lane]) ez = 0.f;
    z = a * ez;
  }
#pragma unroll
  for (int off = 32; off; off >>= 1) z += __shfl_xor(z, off, 64);
  if (lane == 0) lzbuf[wv] = logacc + __logf(z);
  __syncthreads();
  if (threadIdx.x == 0) out[b] = lzbuf[0] - lzbuf[1];
}

// ---------------------------------------------------------------------------
extern "C" void kernel_launch(void* const* d_in, const int* in_sizes, int n_in,
                              void* d_out, int out_size, void* d_ws,
                              size_t ws_size, hipStream_t stream) {
  (void)in_sizes; (void)n_in; (void)out_size; (void)ws_size;
  const float* feats = (const float*)d_in[0];
  const int* tags = (const int*)d_in[1];
  const int* lens = (const int*)d_in[2];
  const float* W = (const float*)d_in[3];
  const float* bias = (const float*)d_in[4];
  const float* begin = (const float*)d_in[5];
  const float* trans = (const float*)d_in[6];
  const float* endt = (const float*)d_in[7];
  const int* bc = (const int*)d_in[8];
  const int* ec = (const int*)d_in[9];
  const int* tc = (const int*)d_in[10];

  float* E = (float*)d_ws;  // T*B*L floats = 6 MB scratch, exp(emissions)
  float* out = (float*)d_out;

  emis_gemm<<<dim3(TB_ / 64), dim3(256), 0, stream>>>(feats, W, bias, E);
  crf_scan<<<dim3(B_), dim3(128), 0, stream>>>(E, tags, lens, begin, trans,
                                               endt, bc, ec, tc, out);
}

// Round 8
// 425.729 us; speedup vs baseline: 1.0861x; 1.0861x over previous
//
#include <hip/hip_runtime.h>

// Problem constants (from reference): T=1024, B=32, D=768, L=48
#define T_ 1024
#define B_ 32
#define D_ 768
#define L_ 48
#define TB_ (T_ * B_)   // 32768 rows of the emissions GEMM

typedef __attribute__((ext_vector_type(4))) float f32x4;

// ---------------------------------------------------------------------------
// Kernel A: E = exp(feats @ W + b)   (fp32, M=32768 N=48 K=768) — UNCHANGED
// this round.  Three structurally different versions (128-row/1-block,
// double-buffered, 64-row/2-block) all measured ~190-200 µs vs a ~20 µs
// model floor; that invariant needs counter evidence, and with the scan
// dropping below ~190 µs this kernel enters the rocprof top-5 next round.
// ---------------------------------------------------------------------------
__global__ __launch_bounds__(256, 2) void emis_gemm(
    const float* __restrict__ feats, const float* __restrict__ W,
    const float* __restrict__ bias, float* __restrict__ E) {
  __shared__ float fbuf[64 * 64];    // row-major, 16 chunks of 16B per row
  __shared__ float wbuf[48 * 68];    // wbuf[j][ko], padded
  const int tid = threadIdx.x;
  const int wv = tid >> 6;           // wave id 0..3
  const int lane = tid & 63;
  const int cg = tid & 7;            // col group -> cols c0..c0+5
  const int rg = tid >> 3;           // row group 0..31 -> rows rg, rg+32
  const int c0 = cg * 6;
  const int rowbase = blockIdx.x * 64;
  const int r7 = rg & 7;
  const int r_in = lane >> 4;        // 0..3 row-within-gload_lds
  const int slot = lane & 15;

  float acc[2][6];
#pragma unroll
  for (int i = 0; i < 2; i++)
#pragma unroll
    for (int c = 0; c < 6; c++) acc[i][c] = 0.f;

  for (int kc = 0; kc < D_; kc += 64) {
    __syncthreads();  // previous chunk's reads complete before overwrite

    // feats chunk: 4 global_load_lds per wave, 4 rows (64 slots) each.
    // LDS slot (r, s) holds global chunk (s ^ (r&7)) -> pre-swizzled source,
    // linear LDS dest (wave-uniform base + lane*16B).
#pragma unroll
    for (int inst = 0; inst < 4; inst++) {
      const int rowstart = wv * 16 + inst * 4;
      const int r = rowstart + r_in;
      const int gch = slot ^ (r & 7);
      const float* g = feats + (size_t)(rowbase + r) * D_ + kc + gch * 4;
      float* l = fbuf + rowstart * 64;  // wave-uniform base
      __builtin_amdgcn_global_load_lds(
          (const __attribute__((address_space(1))) uint32_t*)g,
          (__attribute__((address_space(3))) uint32_t*)l, 16, 0, 0);
    }

    // W chunk transposed: wbuf[j][ko] = W[kc+ko][j]
#pragma unroll
    for (int i = 0; i < 12; i++) {
      const int idx = tid + i * 256;  // 0..3071
      const int ko = idx / 48;
      const int j = idx - ko * 48;
      wbuf[j * 68 + ko] = W[(kc + ko) * L_ + j];
    }

    __syncthreads();  // drains vmcnt (global_load_lds) + lgkm (ds_write)

#pragma unroll 4
    for (int k4 = 0; k4 < 16; k4++) {
      float4 fv[2];
      float4 wv4[6];
      const int sch = (k4 ^ r7) << 2;  // swizzled chunk offset (floats)
#pragma unroll
      for (int i = 0; i < 2; i++)
        fv[i] = *(const float4*)(fbuf + (rg + 32 * i) * 64 + sch);
#pragma unroll
      for (int cc = 0; cc < 6; cc++)
        wv4[cc] = *(const float4*)(wbuf + (c0 + cc) * 68 + k4 * 4);
#pragma unroll
      for (int i = 0; i < 2; i++) {
#pragma unroll
        for (int cc = 0; cc < 6; cc++) {
          acc[i][cc] = fmaf(fv[i].x, wv4[cc].x, acc[i][cc]);
          acc[i][cc] = fmaf(fv[i].y, wv4[cc].y, acc[i][cc]);
          acc[i][cc] = fmaf(fv[i].z, wv4[cc].z, acc[i][cc]);
          acc[i][cc] = fmaf(fv[i].w, wv4[cc].w, acc[i][cc]);
        }
      }
    }
  }

  // epilogue: E = exp(acc + bias), rows rg, rg+32, cols c0..c0+5
#pragma unroll
  for (int i = 0; i < 2; i++) {
    float* dst = E + (size_t)(rowbase + rg + 32 * i) * L_ + c0;
#pragma unroll
    for (int cc = 0; cc < 6; cc += 2) {
      float2 v;
      v.x = __expf(acc[i][cc + 0] + bias[c0 + cc + 0]);
      v.y = __expf(acc[i][cc + 1] + bias[c0 + cc + 1]);
      *(float2*)(dst + cc) = v;
    }
  }
}

// ---------------------------------------------------------------------------
// Kernel B: ONE WAVE PER BLOCK, one pass per block (grid = 2*B = 64 blocks,
// 64 blocks <= 256 CUs so each wave owns a private DS pipe).
// Round-7 evidence: 640 cyc/step with 48 ds_read_b128/CU/step (12 state +
// 12 P, x2 waves) at ~12 cyc each -> DS-THROUGHPUT-bound.  Fixes:
//   - P back in REGISTERS (demand ~90; round-7 proved plain launch_bounds
//     grants 112 VGPRs — the earlier 64-68 caps came with the ",1" variant;
//     amdgpu_waves_per_eu(1) added as explicit allocator headroom).
//   - pass-per-block: DS ops/step/CU drop 26 -> 13 (12 broadcast state
//     reads + 1 publish write), well under the ~350-cyc serial latency path
//     (publish -> 12 broadcast ds_read_b128 -> 48 FMAs in 4 chains).
//   - rescale (t%8==1) with zero cross-lane ops: m = max over the same
//     broadcast state reads (lane-uniform by construction), folded into
//     this step's emission multiply; logacc += log(m).  Worst unscaled
//     stretch <= 11 steps, far inside fp32 range.
//   - combine: atomicAdd(out+b, +/-logZ) — exactly 2 commutative fp adds
//     per element (order-independent result), memset'd before launch.
// Parity: state(t=0) in parity 0; step i reads i&1, writes (i+1)&1; 4-step
// body keeps bodies starting at parity 0; tail continues from parity 0.
// ---------------------------------------------------------------------------
__global__ __launch_bounds__(64)
__attribute__((amdgpu_waves_per_eu(1))) void crf_scan(
    const float* __restrict__ E, const int* __restrict__ tags,
    const int* __restrict__ lens, const float* __restrict__ begin,
    const float* __restrict__ trans, const float* __restrict__ endt,
    const int* __restrict__ bc, const int* __restrict__ ec,
    const int* __restrict__ tc, float* __restrict__ out) {
  __shared__ __align__(16) float sbuf[2][64];  // [parity][slot]
  const int s = blockIdx.x;
  const int pass = s & 1;   // 0 = unconstrained fwd, 1 = constrained partial
  const int b = s >> 1;
  const int lane = threadIdx.x;
  const bool act = lane < L_;
  const bool par = (pass == 1);
  const int len = lens[b];            // in [512, 1024]
  const int stride = B_ * L_;
  const int base = b * L_ + (act ? lane : 0);  // clamped for lanes 48..63

  // Transition row in registers: P[k] = exp(trans[lane][k]); zero for
  // inactive lanes; constraint-masked on the partial pass.
  float P[L_];
#pragma unroll
  for (int k = 0; k < L_; k++) P[k] = 0.f;
  if (act) {
#pragma unroll
    for (int k = 0; k < L_; k++) {
      float v = __expf(trans[lane * L_ + k]);
      if (par && tc[lane * L_ + k]) v = 0.f;
      P[k] = v;
    }
  }

  // init: a0 = E[0]*exp(begin); partial pass additionally masked by bc/tags[0]
  float a = 0.f;
  if (act) {
    a = E[base] * __expf(begin[lane]);
    if (par && (bc[lane] || tags[base])) a = 0.f;
  }
  float logacc = 0.f;

  sbuf[0][lane] = a;  // state(t=0) -> parity 0

  // One recurrence step.  resc: divide this step's output by m = max of the
  // input state (computed from the same broadcast reads) and log-accumulate.
  auto step = [&](int i, float ev, int tg, bool resc) {
    const f32x4* src = (const f32x4*)sbuf[i & 1];
    float s0 = 0.f, s1 = 0.f, s2 = 0.f, s3 = 0.f;
    f32x4 mx = {0.f, 0.f, 0.f, 0.f};  // state is non-negative
#pragma unroll
    for (int c = 0; c < 12; c++) {
      const f32x4 q = src[c];  // broadcast read: all lanes same address
      if (resc) {
        mx.x = fmaxf(mx.x, q.x);
        mx.y = fmaxf(mx.y, q.y);
        mx.z = fmaxf(mx.z, q.z);
        mx.w = fmaxf(mx.w, q.w);
      }
      s0 = fmaf(q.x, P[4 * c + 0], s0);
      s1 = fmaf(q.y, P[4 * c + 1], s1);
      s2 = fmaf(q.z, P[4 * c + 2], s2);
      s3 = fmaf(q.w, P[4 * c + 3], s3);
    }
    float evp = ev;
    if (resc) {
      float m = fmaxf(fmaxf(mx.x, mx.y), fmaxf(mx.z, mx.w));
      m = fmaxf(m, 1e-30f);     // uniform across lanes (same broadcast data)
      logacc += __logf(m);
      evp = ev * (1.f / m);
    }
    float u = ((s0 + s1) + (s2 + s3)) * evp;
    if (tg) u = 0.f;  // tg is always 0 on the fwd pass
    a = u;
    sbuf[(i + 1) & 1][lane] = u;  // publish for the next step
  };

  // preload emissions/tags for t = 1..4 (len >= 512 so always valid)
  float e4[4];
  int tg4[4];
#pragma unroll
  for (int i = 0; i < 4; i++) {
    e4[i] = E[(size_t)(1 + i) * stride + base];
    tg4[i] = par ? tags[(size_t)(1 + i) * stride + base] : 0;
  }

  int t = 1;  // bodies start at t == 1 (mod 4); rescale when t == 1 (mod 8)
  for (; t + 4 <= len; t += 4) {
    float p4[4];
    int q4[4];
#pragma unroll
    for (int i = 0; i < 4; i++) {
      int tt = t + 4 + i;
      tt = (tt < len) ? tt : (len - 1);
      p4[i] = E[(size_t)tt * stride + base];
      q4[i] = par ? tags[(size_t)tt * stride + base] : 0;
    }
    if ((t & 7) == 1) {
      step(0, e4[0], tg4[0], true);   // specialized resc=true expansion
    } else {
      step(0, e4[0], tg4[0], false);
    }
    step(1, e4[1], tg4[1], false);
    step(2, e4[2], tg4[2], false);
    step(3, e4[3], tg4[3], false);
#pragma unroll
    for (int i = 0; i < 4; i++) { e4[i] = p4[i]; tg4[i] = q4[i]; }
  }
  // tail: at most 3 steps; e4 holds times t..t+3 (clamped); parity continues
#pragma unroll
  for (int i = 0; i < 4; i++) {
    if (t + i < len) step(i, e4[i], tg4[i], false);
  }

  // readout: logZ = logacc + log(sum_j a[j]*exp(end[j]))
  float z = 0.f;
  if (act) {
    float ez = __expf(endt[lane]);
    if (par && ec[lane]) ez = 0.f;
    z = a * ez;
  }
#pragma unroll
  for (int off = 32; off; off >>= 1) z += __shfl_xor(z, off, 64);
  const float logZ = logacc + __logf(z);
  if (lane == 0) atomicAdd(out + b, par ? -logZ : logZ);
}

// ---------------------------------------------------------------------------
extern "C" void kernel_launch(void* const* d_in, const int* in_sizes, int n_in,
                              void* d_out, int out_size, void* d_ws,
                              size_t ws_size, hipStream_t stream) {
  (void)in_sizes; (void)n_in; (void)out_size; (void)ws_size;
  const float* feats = (const float*)d_in[0];
  const int* tags = (const int*)d_in[1];
  const int* lens = (const int*)d_in[2];
  const float* W = (const float*)d_in[3];
  const float* bias = (const float*)d_in[4];
  const float* begin = (const float*)d_in[5];
  const float* trans = (const float*)d_in[6];
  const float* endt = (const float*)d_in[7];
  const int* bc = (const int*)d_in[8];
  const int* ec = (const int*)d_in[9];
  const int* tc = (const int*)d_in[10];

  float* E = (float*)d_ws;  // T*B*L floats = 6 MB scratch, exp(emissions)
  float* out = (float*)d_out;

  hipMemsetAsync(d_out, 0, B_ * sizeof(float), stream);

  emis_gemm<<<dim3(TB_ / 64), dim3(256), 0, stream>>>(feats, W, bias, E);
  crf_scan<<<dim3(2 * B_), dim3(64), 0, stream>>>(E, tags, lens, begin, trans,
                                                  endt, bc, ec, tc, out);
}